// Round 1
// baseline (280.545 us; speedup 1.0000x reference)
//
#include <hip/hip_runtime.h>

// Problem constants (from reference): N=32, C=3, H=W=512, SCALE=1 -> OUT=512,
// A=512 (attention length), DENSE=4 -> thr0 = 4*512/512 = 4.0, ITERS=5.
#define NB   32
#define NC   3
#define HH   512
#define WW   512
#define AA   512
#define OUT  512

// ---------------- wave / block reductions ----------------
__device__ __forceinline__ float wave_sum(float v) {
#pragma unroll
    for (int m = 32; m > 0; m >>= 1) v += __shfl_xor(v, m, 64);
    return v;
}
__device__ __forceinline__ float wave_max(float v) {
#pragma unroll
    for (int m = 32; m > 0; m >>= 1) v = fmaxf(v, __shfl_xor(v, m, 64));
    return v;
}

// 512 threads = 8 waves. red[] needs >= 8 floats.
__device__ __forceinline__ float block_sum(float v, float* red, int tid) {
    v = wave_sum(v);
    if ((tid & 63) == 0) red[tid >> 6] = v;
    __syncthreads();
    float r = red[0];
#pragma unroll
    for (int k = 1; k < 8; ++k) r += red[k];
    __syncthreads();
    return r;
}
__device__ __forceinline__ float block_max(float v, float* red, int tid) {
    v = wave_max(v);
    if ((tid & 63) == 0) red[tid >> 6] = v;
    __syncthreads();
    float r = red[0];
#pragma unroll
    for (int k = 1; k < 8; ++k) r = fmaxf(r, red[k]);
    __syncthreads();
    return r;
}

// ---------------- kernel 1: iterative clip + inverse CDF ----------------
// One block per batch n; thread tid owns ax[tid], ay[tid].
__global__ __launch_bounds__(512) void clip_cdf_kernel(
    const float* __restrict__ attx, const float* __restrict__ atty,
    float* __restrict__ px, float* __restrict__ py)
{
    __shared__ float red[8];
    __shared__ float cs[AA];

    const int n   = blockIdx.x;
    const int tid = threadIdx.x;

    float ax = attx[n * AA + tid];
    float ay = atty[n * AA + tid];

    // normalize * OUT
    float sx = block_sum(ax, red, tid);
    float sy = block_sum(ay, red, tid);
    ax = ax / sx * (float)OUT;
    ay = ay / sy * (float)OUT;

    // 5 clip iterations
#pragma unroll
    for (int it = 0; it < 5; ++it) {
        float mx = block_max(ax, red, tid);
        float my = block_max(ay, red, tid);
        float tv = fminf(mx, my);
        if (it == 0) tv = fminf(tv, 4.0f);   // thr0 = DENSE*OUT/A
        ax = fminf(ax, tv);
        ay = fminf(ay, tv);
        float sax = block_sum(ax, red, tid);
        float say = block_sum(ay, red, tid);
        ax += ((float)OUT - sax) * (1.0f / (float)AA);
        ay += ((float)OUT - say) * (1.0f / (float)AA);
    }

    // inverse CDF, done twice (ax -> px, ay -> py)
#pragma unroll
    for (int which = 0; which < 2; ++which) {
        float v = (which == 0) ? ax : ay;
        // inclusive scan (Hillis-Steele) into cs[]
        cs[tid] = v;
        __syncthreads();
#pragma unroll
        for (int off = 1; off < AA; off <<= 1) {
            float add = (tid >= off) ? cs[tid - off] : 0.0f;
            __syncthreads();
            cs[tid] += add;
            __syncthreads();
        }
        float total = cs[AA - 1];
        float step  = total / (float)OUT;
        float tk    = ((float)tid + 0.5f) * step;

        // searchsorted side='left': first j with cs[j] >= tk
        int lo = 0, hi = AA;
        while (lo < hi) {
            int mid = (lo + hi) >> 1;
            if (cs[mid] < tk) lo = mid + 1; else hi = mid;
        }
        int j = lo; if (j > AA - 1) j = AA - 1;
        float cprev = (j > 0) ? cs[j - 1] : 0.0f;
        float dens  = cs[j] - cprev;
        float p     = (float)j + (tk - cprev) / fmaxf(dens, 1e-6f);
        float g     = 2.0f * p / (float)AA - 1.0f;
        if (which == 0) px[n * OUT + tid] = g;
        else            py[n * OUT + tid] = g;
        __syncthreads();
    }
}

// ---------------- kernel 2: grid build + bilinear sample ----------------
// One block per output row (n, i); 256 threads x 2 pixels.
__global__ __launch_bounds__(256) void sample_kernel(
    const float* __restrict__ data, const float* __restrict__ px,
    const float* __restrict__ py, float* __restrict__ sampled,
    float2* __restrict__ grid)
{
    const int bid = blockIdx.x;          // n*OUT + i
    const int n   = bid >> 9;            // / 512
    const int i   = bid & (OUT - 1);

    const float gy  = py[n * OUT + i];
    const float iy  = (gy + 1.0f) * 0.5f * (float)(HH - 1);
    const float y0f = floorf(iy);
    const float wy  = iy - y0f;
    int y0 = (int)y0f;
    y0 = max(0, min(y0, HH - 1));
    const int y1 = min(y0 + 1, HH - 1);

    const float* dbase = data + (size_t)n * NC * HH * WW;
    float*       sbase = sampled + (size_t)n * NC * HH * WW + (size_t)i * WW;
    float2*      gbase = grid + ((size_t)n * OUT + i) * OUT;

    const float omwy = 1.0f - wy;

#pragma unroll
    for (int rep = 0; rep < 2; ++rep) {
        const int j = threadIdx.x + rep * 256;
        const float gx  = px[n * OUT + j];
        const float ix  = (gx + 1.0f) * 0.5f * (float)(WW - 1);
        const float x0f = floorf(ix);
        const float wx  = ix - x0f;
        int x0 = (int)x0f;
        x0 = max(0, min(x0, WW - 1));
        const int x1 = min(x0 + 1, WW - 1);
        const float omwx = 1.0f - wx;

        gbase[j] = make_float2(gx, gy);

#pragma unroll
        for (int c = 0; c < NC; ++c) {
            const float* r0 = dbase + ((size_t)c * HH + y0) * WW;
            const float* r1 = dbase + ((size_t)c * HH + y1) * WW;
            const float v00 = r0[x0];
            const float v01 = r0[x1];
            const float v10 = r1[x0];
            const float v11 = r1[x1];
            const float top = v00 * omwx + v01 * wx;
            const float bot = v10 * omwx + v11 * wx;
            sbase[(size_t)c * HH * WW + j] = top * omwy + bot * wy;
        }
    }
}

extern "C" void kernel_launch(void* const* d_in, const int* in_sizes, int n_in,
                              void* d_out, int out_size, void* d_ws, size_t ws_size,
                              hipStream_t stream) {
    const float* data = (const float*)d_in[0];
    const float* attx = (const float*)d_in[1];
    const float* atty = (const float*)d_in[2];

    float* px = (float*)d_ws;                 // NB*OUT floats
    float* py = px + NB * OUT;                // NB*OUT floats

    float*  out     = (float*)d_out;
    float*  sampled = out;                                   // (N,C,H,W)
    float2* grid    = (float2*)(out + (size_t)NB * NC * HH * WW); // (N,H,W,2)

    clip_cdf_kernel<<<NB, 512, 0, stream>>>(attx, atty, px, py);
    sample_kernel<<<NB * OUT, 256, 0, stream>>>(data, px, py, sampled, grid);
}

// Round 3
// 253.292 us; speedup vs baseline: 1.1076x; 1.1076x over previous
//
#include <hip/hip_runtime.h>

// Problem constants: N=32, C=3, H=W=512, SCALE=1 -> OUT=512, A=512,
// DENSE=4 -> thr0 = 4.0, ITERS=5.
#define NB   32
#define NC   3
#define HH   512
#define WW   512
#define AA   512
#define OUT  512

// ---------------- wave / block reductions (known-good R1 versions) ----------
__device__ __forceinline__ float wave_sum(float v) {
#pragma unroll
    for (int m = 32; m > 0; m >>= 1) v += __shfl_xor(v, m, 64);
    return v;
}
__device__ __forceinline__ float wave_max(float v) {
#pragma unroll
    for (int m = 32; m > 0; m >>= 1) v = fmaxf(v, __shfl_xor(v, m, 64));
    return v;
}

// 512 threads = 8 waves. red[] needs >= 8 floats.
__device__ __forceinline__ float block_sum(float v, float* red, int tid) {
    v = wave_sum(v);
    if ((tid & 63) == 0) red[tid >> 6] = v;
    __syncthreads();
    float r = red[0];
#pragma unroll
    for (int k = 1; k < 8; ++k) r += red[k];
    __syncthreads();
    return r;
}
__device__ __forceinline__ float block_max(float v, float* red, int tid) {
    v = wave_max(v);
    if ((tid & 63) == 0) red[tid >> 6] = v;
    __syncthreads();
    float r = red[0];
#pragma unroll
    for (int k = 1; k < 8; ++k) r = fmaxf(r, red[k]);
    __syncthreads();
    return r;
}

// ---------------- kernel 1: iterative clip + inverse CDF (exact R1) --------
__global__ __launch_bounds__(512) void clip_cdf_kernel(
    const float* __restrict__ attx, const float* __restrict__ atty,
    float* __restrict__ px, float* __restrict__ py)
{
    __shared__ float red[8];
    __shared__ float cs[AA];

    const int n   = blockIdx.x;
    const int tid = threadIdx.x;

    float ax = attx[n * AA + tid];
    float ay = atty[n * AA + tid];

    // normalize * OUT
    float sx = block_sum(ax, red, tid);
    float sy = block_sum(ay, red, tid);
    ax = ax / sx * (float)OUT;
    ay = ay / sy * (float)OUT;

    // 5 clip iterations
#pragma unroll
    for (int it = 0; it < 5; ++it) {
        float mx = block_max(ax, red, tid);
        float my = block_max(ay, red, tid);
        float tv = fminf(mx, my);
        if (it == 0) tv = fminf(tv, 4.0f);   // thr0 = DENSE*OUT/A
        ax = fminf(ax, tv);
        ay = fminf(ay, tv);
        float sax = block_sum(ax, red, tid);
        float say = block_sum(ay, red, tid);
        ax += ((float)OUT - sax) * (1.0f / (float)AA);
        ay += ((float)OUT - say) * (1.0f / (float)AA);
    }

    // inverse CDF, done twice (ax -> px, ay -> py)
#pragma unroll
    for (int which = 0; which < 2; ++which) {
        float v = (which == 0) ? ax : ay;
        // inclusive scan (Hillis-Steele) into cs[]
        cs[tid] = v;
        __syncthreads();
#pragma unroll
        for (int off = 1; off < AA; off <<= 1) {
            float add = (tid >= off) ? cs[tid - off] : 0.0f;
            __syncthreads();
            cs[tid] += add;
            __syncthreads();
        }
        float total = cs[AA - 1];
        float step  = total / (float)OUT;
        float tk    = ((float)tid + 0.5f) * step;

        // searchsorted side='left': first j with cs[j] >= tk
        int lo = 0, hi = AA;
        while (lo < hi) {
            int mid = (lo + hi) >> 1;
            if (cs[mid] < tk) lo = mid + 1; else hi = mid;
        }
        int j = lo; if (j > AA - 1) j = AA - 1;
        float cprev = (j > 0) ? cs[j - 1] : 0.0f;
        float dens  = cs[j] - cprev;
        float p     = (float)j + (tk - cprev) / fmaxf(dens, 1e-6f);
        float g     = 2.0f * p / (float)AA - 1.0f;
        if (which == 0) px[n * OUT + tid] = g;
        else            py[n * OUT + tid] = g;
        __syncthreads();
    }
}

// ---------------- kernel 2: grid build + bilinear sample -------------------
// R1 structure (no swizzle), ONE change: 6 input rows staged in LDS with
// coalesced float4 loads; bilinear gathers read LDS instead of global.
__global__ __launch_bounds__(256) void sample_kernel(
    const float* __restrict__ data, const float* __restrict__ px,
    const float* __restrict__ py, float* __restrict__ sampled,
    float2* __restrict__ grid)
{
    __shared__ float lrow[6][WW];   // 12 KB: rows (y0,c0..2), (y1,c0..2)

    const int bid = blockIdx.x;          // n*OUT + i
    const int n   = bid >> 9;            // / 512
    const int i   = bid & (OUT - 1);

    const float gy  = py[n * OUT + i];
    const float iy  = (gy + 1.0f) * 0.5f * (float)(HH - 1);
    const float y0f = floorf(iy);
    const float wy  = iy - y0f;
    int y0 = (int)y0f;
    y0 = max(0, min(y0, HH - 1));
    const int y1 = min(y0 + 1, HH - 1);

    const float* dbase = data + (size_t)n * NC * HH * WW;

    // stage 6 rows: 768 float4s over 256 threads (3 each), coalesced
#pragma unroll
    for (int k = 0; k < 3; ++k) {
        const int idx = threadIdx.x + k * 256;   // 0..767
        const int row = idx >> 7;                // 0..5 (128 float4 per row)
        const int q   = idx & 127;               // float4 index within row
        const int c   = (row < 3) ? row : row - 3;
        const int y   = (row < 3) ? y0 : y1;
        const float4 v = ((const float4*)(dbase + ((size_t)c * HH + y) * WW))[q];
        ((float4*)&lrow[row][0])[q] = v;
    }
    __syncthreads();

    float*  sbase = sampled + (size_t)n * NC * HH * WW + (size_t)i * WW;
    float2* gbase = grid + ((size_t)n * OUT + i) * OUT;
    const float omwy = 1.0f - wy;

#pragma unroll
    for (int rep = 0; rep < 2; ++rep) {
        const int j = threadIdx.x + rep * 256;
        const float gx  = px[n * OUT + j];
        const float ix  = (gx + 1.0f) * 0.5f * (float)(WW - 1);
        const float x0f = floorf(ix);
        const float wx  = ix - x0f;
        int x0 = (int)x0f;
        x0 = max(0, min(x0, WW - 1));
        const int x1 = min(x0 + 1, WW - 1);
        const float omwx = 1.0f - wx;

        gbase[j] = make_float2(gx, gy);

#pragma unroll
        for (int c = 0; c < NC; ++c) {
            const float v00 = lrow[c][x0];
            const float v01 = lrow[c][x1];
            const float v10 = lrow[3 + c][x0];
            const float v11 = lrow[3 + c][x1];
            const float top = v00 * omwx + v01 * wx;
            const float bot = v10 * omwx + v11 * wx;
            sbase[(size_t)c * HH * WW + j] = top * omwy + bot * wy;
        }
    }
}

extern "C" void kernel_launch(void* const* d_in, const int* in_sizes, int n_in,
                              void* d_out, int out_size, void* d_ws, size_t ws_size,
                              hipStream_t stream) {
    const float* data = (const float*)d_in[0];
    const float* attx = (const float*)d_in[1];
    const float* atty = (const float*)d_in[2];

    float* px = (float*)d_ws;                 // NB*OUT floats
    float* py = px + NB * OUT;                // NB*OUT floats

    float*  out     = (float*)d_out;
    float*  sampled = out;                                        // (N,C,H,W)
    float2* grid    = (float2*)(out + (size_t)NB * NC * HH * WW); // (N,H,W,2)

    clip_cdf_kernel<<<NB, 512, 0, stream>>>(attx, atty, px, py);
    sample_kernel<<<NB * OUT, 256, 0, stream>>>(data, px, py, sampled, grid);
}